// Round 10
// baseline (939.154 us; speedup 1.0000x reference)
//
#include <hip/hip_runtime.h>

// B=2, streams=2, N=1024, D=256, H=4, DH=64, L=18
// Row layout: r = s*2048 + b*1024 + n  (M=4096 rows)
// bf16 MFMA 16x16x32: A-frag lane=A[m=lane&15][k=quad*8+j]; B-frag B[k=quad*8+j][n=lane&15]
// C/D: col=lane&15, row=quad*4+reg
// LDS XOR swizzle: 16B chunk c of row r stored at slot (c ^ (r&7)).
// BN stats PER STREAM (2048 rows each), accumulated via global fp32 atomics.
// R9->R10: GEMMs back to BM=64 (B-panel staged once per 64 rows, halving per-CU
//   LDS-fill for the same MFMA work). Grids 384/256/256, XCD-swizzled, 2-deep
//   counted-vmcnt K-loops (stage = 6 loads/wave -> vmcnt(6)).
// NOTE (R5 lesson): persistent kernel + homemade grid barrier = ~69us/barrier on
// CDNA4; kernel boundaries (~4us) are the cheap sync.

typedef __attribute__((ext_vector_type(8))) short bf16x8;
typedef __attribute__((ext_vector_type(4))) short bf16x4;
typedef __attribute__((ext_vector_type(4))) float floatx4;

__device__ __forceinline__ short f2b(float f) {   // fp32 -> bf16 RNE
  unsigned u = __builtin_bit_cast(unsigned, f);
  unsigned r = (u + 0x7FFFu + ((u >> 16) & 1u)) >> 16;
  return (short)r;
}
__device__ __forceinline__ unsigned pack2(float a, float b) {
  return (unsigned)(unsigned short)f2b(a) | ((unsigned)(unsigned short)f2b(b) << 16);
}
// split a,b into bf16-hi pair (packed) and fp32-residual bf16 pair (packed)
__device__ __forceinline__ void split2(float a, float b, unsigned& h, unsigned& l) {
  unsigned short ha = (unsigned short)f2b(a), hb = (unsigned short)f2b(b);
  float fa = __builtin_bit_cast(float, (unsigned)ha << 16);
  float fb = __builtin_bit_cast(float, (unsigned)hb << 16);
  h = (unsigned)ha | ((unsigned)hb << 16);
  l = pack2(a - fa, b - fb);
}

__device__ __forceinline__ void gl2lds16(const void* g, void* l) {
  __builtin_amdgcn_global_load_lds(
      (const __attribute__((address_space(1))) unsigned*)g,
      (__attribute__((address_space(3))) unsigned*)l, 16, 0, 0);
}

__device__ __forceinline__ floatx4 mfma16_bf16(bf16x4 a, bf16x4 b, floatx4 c) {
#if __has_builtin(__builtin_amdgcn_mfma_f32_16x16x16_bf16)
  return __builtin_amdgcn_mfma_f32_16x16x16_bf16(a, b, c, 0, 0, 0);
#elif __has_builtin(__builtin_amdgcn_mfma_f32_16x16x16bf16_1k)
  return __builtin_amdgcn_mfma_f32_16x16x16bf16_1k(a, b, c, 0, 0, 0);
#else
  asm volatile("v_mfma_f32_16x16x16_bf16 %0, %1, %2, %0" : "+v"(c) : "v"(a), "v"(b));
  return c;
#endif
}

#define BARW   asm volatile("s_barrier" ::: "memory")
#define WAITV8 asm volatile("s_waitcnt vmcnt(8)" ::: "memory")
#define WAITV6 asm volatile("s_waitcnt vmcnt(6)" ::: "memory")
#define WAITV4 asm volatile("s_waitcnt vmcnt(4)" ::: "memory")
#define WAITV0 asm volatile("s_waitcnt vmcnt(0)" ::: "memory")
#define LGKM0  asm volatile("s_waitcnt lgkmcnt(0)" ::: "memory")
#define PRIO1  __builtin_amdgcn_s_setprio(1)
#define PRIO0  __builtin_amdgcn_s_setprio(0)

#define GEMM_IDS                                        \
  const int tid = threadIdx.x;                          \
  const int lane = tid & 63, w = tid >> 6;              \
  const int wy = w >> 1, wx = w & 1;                    \
  const int quad = lane >> 4, l16 = lane & 15;          \
  const int lr = lane >> 3;                             \
  const int lcs = (((lane & 7) ^ lr) & 7) * 8;          \
  const floatx4 z4 = {0.f, 0.f, 0.f, 0.f};

// swizzled MFMA K-step (BM=64, BN=128, wave-tile 32x64)
__device__ __forceinline__ void mfma_step_sw(const short* As, const short* Bs,
                                             int wy, int wx, int quad, int l16,
                                             floatx4 acc[2][4]) {
#pragma unroll
  for (int kk = 0; kk < 2; ++kk) {
    const int sw = (((kk * 4 + quad) ^ (l16 & 7)) * 8);
    bf16x8 a0 = *(const bf16x8*)&As[(wy * 32 + l16) * 64 + sw];
    bf16x8 a1 = *(const bf16x8*)&As[(wy * 32 + 16 + l16) * 64 + sw];
    bf16x8 b[4];
#pragma unroll
    for (int ni = 0; ni < 4; ++ni)
      b[ni] = *(const bf16x8*)&Bs[(wx * 64 + ni * 16 + l16) * 64 + sw];
#pragma unroll
    for (int ni = 0; ni < 4; ++ni) {
      acc[0][ni] = __builtin_amdgcn_mfma_f32_16x16x32_bf16(a0, b[ni], acc[0][ni], 0, 0, 0);
      acc[1][ni] = __builtin_amdgcn_mfma_f32_16x16x32_bf16(a1, b[ni], acc[1][ni], 0, 0, 0);
    }
  }
}

// swizzled MFMA K-step (BM=64, BN=64, wave-tile 32x32)
__device__ __forceinline__ void mfma_step_sw64(const short* As, const short* Bs,
                                               int wy, int wx, int quad, int l16,
                                               floatx4 acc[2][2]) {
#pragma unroll
  for (int kk = 0; kk < 2; ++kk) {
    const int sw = (((kk * 4 + quad) ^ (l16 & 7)) * 8);
    bf16x8 a0 = *(const bf16x8*)&As[(wy * 32 + l16) * 64 + sw];
    bf16x8 a1 = *(const bf16x8*)&As[(wy * 32 + 16 + l16) * 64 + sw];
    bf16x8 b[2];
#pragma unroll
    for (int ni = 0; ni < 2; ++ni)
      b[ni] = *(const bf16x8*)&Bs[(wx * 32 + ni * 16 + l16) * 64 + sw];
#pragma unroll
    for (int ni = 0; ni < 2; ++ni) {
      acc[0][ni] = __builtin_amdgcn_mfma_f32_16x16x32_bf16(a0, b[ni], acc[0][ni], 0, 0, 0);
      acc[1][ni] = __builtin_amdgcn_mfma_f32_16x16x32_bf16(a1, b[ni], acc[1][ni], 0, 0, 0);
    }
  }
}

// ---------- wfuse: F = ow(256x256) @ w1bot(256x512), F^T -> w1t[n][256+kp]
// MFMA with bf16 hi/lo 3-term split. 64x128 tiles, grid 18*16=288.
__global__ __launch_bounds__(256) void wfuse(
    const float* __restrict__ ow, const float* __restrict__ w1,
    short* __restrict__ wbuf) {
  __shared__ short As_h[64 * 64], As_l[64 * 64];
  __shared__ short Bs_h[128 * 64], Bs_l[128 * 64];
  const int blk = blockIdx.x;
  const int layer = blk >> 4, sub = blk & 15;
  const int kp0 = (sub & 3) * 64, n0 = (sub >> 2) * 128;
  const float* A = ow + (size_t)layer * 65536;                 // [kp][i], 256-stride
  const float* Bw = w1 + (size_t)layer * 262144 + 256 * 512;   // [i][n], 512-stride
  short* w1t = wbuf + (size_t)layer * 655360 + 262144;
  GEMM_IDS;
  (void)lr; (void)lcs;
  floatx4 acc[2][4] = {{z4, z4, z4, z4}, {z4, z4, z4, z4}};
  const int ar = tid >> 2, aq = tid & 3;
  const int bn = tid & 127, bkh = tid >> 7;

  for (int s = 0; s < 4; ++s) {
    const int k0 = s * 64;
    const float* Ar = &A[(size_t)(kp0 + ar) * 256 + k0 + aq * 16];
    float4 f0 = *(const float4*)&Ar[0];
    float4 f1 = *(const float4*)&Ar[4];
    float4 f2 = *(const float4*)&Ar[8];
    float4 f3 = *(const float4*)&Ar[12];
    float bv[32];
#pragma unroll
    for (int kk2 = 0; kk2 < 32; ++kk2)
      bv[kk2] = Bw[(size_t)(k0 + bkh * 32 + kk2) * 512 + n0 + bn];

    __syncthreads();
    {
      uint4 hi, lo;
      split2(f0.x, f0.y, hi.x, lo.x);
      split2(f0.z, f0.w, hi.y, lo.y);
      split2(f1.x, f1.y, hi.z, lo.z);
      split2(f1.z, f1.w, hi.w, lo.w);
      int sl = ((aq * 2) ^ (ar & 7)) * 8;
      *(uint4*)&As_h[ar * 64 + sl] = hi;
      *(uint4*)&As_l[ar * 64 + sl] = lo;
      split2(f2.x, f2.y, hi.x, lo.x);
      split2(f2.z, f2.w, hi.y, lo.y);
      split2(f3.x, f3.y, hi.z, lo.z);
      split2(f3.z, f3.w, hi.w, lo.w);
      sl = ((aq * 2 + 1) ^ (ar & 7)) * 8;
      *(uint4*)&As_h[ar * 64 + sl] = hi;
      *(uint4*)&As_l[ar * 64 + sl] = lo;
    }
#pragma unroll
    for (int cc = 0; cc < 4; ++cc) {
      uint4 hi, lo;
      split2(bv[cc * 8 + 0], bv[cc * 8 + 1], hi.x, lo.x);
      split2(bv[cc * 8 + 2], bv[cc * 8 + 3], hi.y, lo.y);
      split2(bv[cc * 8 + 4], bv[cc * 8 + 5], hi.z, lo.z);
      split2(bv[cc * 8 + 6], bv[cc * 8 + 7], hi.w, lo.w);
      int sl = ((bkh * 4 + cc) ^ (bn & 7)) * 8;
      *(uint4*)&Bs_h[bn * 64 + sl] = hi;
      *(uint4*)&Bs_l[bn * 64 + sl] = lo;
    }
    __syncthreads();
    mfma_step_sw(As_h, Bs_h, wy, wx, quad, l16, acc);
    mfma_step_sw(As_h, Bs_l, wy, wx, quad, l16, acc);
    mfma_step_sw(As_l, Bs_h, wy, wx, quad, l16, acc);
  }
#pragma unroll
  for (int mi = 0; mi < 2; ++mi)
#pragma unroll
    for (int ni = 0; ni < 4; ++ni) {
      int col = n0 + wx * 64 + ni * 16 + l16;             // n
      int row0 = kp0 + wy * 32 + mi * 16 + quad * 4;      // kp base
      uint2 uu;
      uu.x = pack2(acc[mi][ni][0], acc[mi][ni][1]);
      uu.y = pack2(acc[mi][ni][2], acc[mi][ni][3]);
      *(uint2*)&w1t[(size_t)col * 512 + 256 + row0] = uu;
    }
}

// ---------- prep kernel:
// blocks [0,2592): wconv transpose+convert, 32k x 128n tiles (16.6KB LDS)
// blocks [2592,2736): bfuse
// blocks [2736,3760): input swap-copy
// blocks [3760,3796): zero psum/psq
__global__ __launch_bounds__(256) void wprep(
    const float* __restrict__ qw, const float* __restrict__ kw,
    const float* __restrict__ vw, const float* __restrict__ w1,
    const float* __restrict__ w2, const float* __restrict__ ob,
    const float* __restrict__ b1, short* __restrict__ wbuf,
    float* __restrict__ beff, const float* __restrict__ desc,
    float* __restrict__ xd, short* __restrict__ xb,
    float* __restrict__ psz) {
  __shared__ float SH[32 * 130];
  int blk = blockIdx.x;
  int t = threadIdx.x;
  if (blk < 2592) {
    int layer = blk / 144;
    int sub2 = blk % 144;
    int sub = sub2 >> 1;          // 0..71, same tile decode as before
    int khalf = sub2 & 1;         // which 32-row half of the 64-row tile
    const float* W; int Kd, Nd, k0, n0; size_t ooff;
    if (sub < 24) {
      int wsel = sub / 8; int tt = sub & 7;
      k0 = (tt >> 1) * 64; n0 = (tt & 1) * 128; Kd = 256; Nd = 256;
      W = (wsel == 0 ? qw : wsel == 1 ? kw : vw) + (size_t)layer * 65536;
      ooff = (size_t)wsel * 65536;
    } else if (sub < 56) {
      int tt = sub - 24; k0 = (tt >> 2) * 64; n0 = (tt & 3) * 128;   // top half of w1
      Kd = 512; Nd = 512; W = w1 + (size_t)layer * 262144; ooff = 262144;
    } else {
      int tt = sub - 56; k0 = (tt >> 1) * 64; n0 = (tt & 1) * 128;
      Kd = 512; Nd = 256; W = w2 + (size_t)layer * 131072; ooff = 524288;
    }
    k0 += khalf * 32;
    short* out = wbuf + (size_t)layer * 655360 + ooff;
    const int rr = t >> 4;          // 0..15
    const int c4 = (t & 15) * 4;
#pragma unroll
    for (int i = 0; i < 2; ++i)
#pragma unroll
      for (int hf = 0; hf < 2; ++hf) {
        float4 v = *(const float4*)&W[(size_t)(k0 + i * 16 + rr) * Nd + n0 + hf * 64 + c4];
        float* tp = &SH[(i * 16 + rr) * 130 + hf * 64 + c4];
        tp[0] = v.x; tp[1] = v.y; tp[2] = v.z; tp[3] = v.w;
      }
    __syncthreads();
    const int n = t >> 1;           // 0..127 col within tile
    const int kh = (t & 1) * 16;    // 16-k half of the 32 rows
    float v[16];
#pragma unroll
    for (int kk = 0; kk < 16; ++kk)
      v[kk] = SH[(kh + kk) * 130 + n];
    unsigned u[8];
#pragma unroll
    for (int j2 = 0; j2 < 8; ++j2) u[j2] = pack2(v[2 * j2], v[2 * j2 + 1]);
    short* op = &out[(size_t)(n0 + n) * Kd + k0 + kh];
    uint4 o1; o1.x = u[0]; o1.y = u[1]; o1.z = u[2]; o1.w = u[3];
    uint4 o2; o2.x = u[4]; o2.y = u[5]; o2.z = u[6]; o2.w = u[7];
    *(uint4*)&op[0] = o1;
    *(uint4*)&op[8] = o2;
  } else if (blk < 2736) {
    int bb = blk - 2592;
    int layer = bb >> 3;
    int n0 = (bb & 7) * 64;
    const float* obL = ob + (size_t)layer * 256;
    const float* w1L = w1 + (size_t)layer * 262144 + 256 * 512;
    int n = n0 + (t & 63);
    int part = t >> 6;
    float s = 0.f;
    for (int i = part * 64; i < part * 64 + 64; ++i)
      s += obL[i] * w1L[(size_t)i * 512 + n];
    SH[part * 64 + (t & 63)] = s;
    __syncthreads();
    if (t < 64) {
      float tot = SH[t] + SH[64 + t] + SH[128 + t] + SH[192 + t] +
                  b1[(size_t)layer * 512 + n0 + t];
      beff[(size_t)layer * 512 + n0 + t] = tot;
    }
  } else if (blk < 3760) {
    int idx = (blk - 2736) * 256 + t;
    int fi = idx << 2;
    int hi = (fi >> 19) & 1;
    int lo = (fi >> 18) & 1;
    int sj = (fi & ~(3 << 18)) | (lo << 19) | (hi << 18);
    float4 v = *(const float4*)&desc[sj];
    *(float4*)&xd[fi] = v;
    uint2 uu; uu.x = pack2(v.x, v.y); uu.y = pack2(v.z, v.w);
    *(uint2*)&xb[fi] = uu;
  } else {
    int idx = (blk - 3760) * 1024 + t * 4;
    float4 zz = {0.f, 0.f, 0.f, 0.f};
    *(float4*)&psz[idx] = zz;
  }
}

// ---------- fused QKV GEMM: BM=64, 1-D grid 384, XCD swizzle, cb-fast.
// 2-deep counted-vmcnt pipeline, 4 k-steps. LDS 48KB -> 3 blocks/CU.
__global__ __launch_bounds__(256, 3) void gemm_qkv(
    const short* __restrict__ xb, const short* __restrict__ wbufL,
    const float* __restrict__ qb_, const float* __restrict__ kb_,
    const float* __restrict__ vb_,
    short* __restrict__ q, short* __restrict__ kout, short* __restrict__ vT,
    int cross) {
  __shared__ short SM[2 * 4096 + 2 * 8192];   // As[2][4096] | Bs[2][8192]
  short* As = SM;
  short* Bs = SM + 8192;
  const int bid = blockIdx.x;
  const int swz = (bid & 7) * 48 + (bid >> 3);   // 384/8 = 48
  const int rb = (swz / 6) * 64;
  const int cb = (swz % 6) * 128;
  const int seg = cb >> 8;
  const int cbl = cb & 255;
  int arb = rb;
  if (seg) arb = (rb & 2047) | ((((rb >> 11) ^ cross) & 1) << 11);
  const short* A = xb + (size_t)arb * 256;
  const short* Wt = wbufL + (size_t)seg * 65536 + (size_t)cbl * 256;
  const float* bias = (seg == 0 ? qb_ : seg == 1 ? kb_ : vb_) + cbl;
  GEMM_IDS;
  floatx4 acc[2][4] = {{z4, z4, z4, z4}, {z4, z4, z4, z4}};

#define QKV_STAGE(s, buf)                                                          \
  {                                                                                \
    int k0 = (s) * 64;                                                             \
    gl2lds16(&A[(size_t)(w * 8 + lr) * 256 + k0 + lcs], &As[(buf) * 4096 + (w * 8) * 64]); \
    gl2lds16(&A[(size_t)(32 + w * 8 + lr) * 256 + k0 + lcs], &As[(buf) * 4096 + (32 + w * 8) * 64]); \
    _Pragma("unroll") for (int i = 0; i < 4; ++i)                                  \
      gl2lds16(&Wt[(size_t)(i * 32 + w * 8 + lr) * 256 + k0 + lcs],                \
               &Bs[(buf) * 8192 + (i * 32 + w * 8) * 64]);                         \
  }

  QKV_STAGE(0, 0);
  QKV_STAGE(1, 1);
  for (int s = 0; s < 4; ++s) {
    int buf = s & 1;
    if (s < 3) { WAITV6; } else { WAITV0; }
    BARW;
    mfma_step_sw(&As[buf * 4096], &Bs[buf * 8192], wy, wx, quad, l16, acc);
    BARW;
    if (s < 2) QKV_STAGE(s + 2, buf);
  }

  if (seg < 2) {
    short* C = (seg == 0 ? q : kout) + (size_t)rb * 256 + cbl;
#pragma unroll
    for (int mi = 0; mi < 2; ++mi)
#pragma unroll
      for (int ni = 0; ni < 4; ++ni) {
        int col = wx * 64 + ni * 16 + l16;
        float bc = bias[col];
#pragma unroll
        for (int reg = 0; reg < 4; ++reg) {
          int row = wy * 32 + mi * 16 + quad * 4 + reg;
          C[(size_t)row * 256 + col] = f2b(acc[mi][ni][reg] + bc);
        }
      }
  } else {
    // all LDS reads done (trailing BARW above); reuse SM as wave-local scratch
    short* T = SM + w * 2560;       // 64 dims x 40 (pad), wave-local
    const int sb = rb >> 10;
    const int hh = (cbl >> 6) + wx;
    const int z = sb * 4 + hh;
#pragma unroll
    for (int mi = 0; mi < 2; ++mi)
#pragma unroll
      for (int ni = 0; ni < 4; ++ni) {
        int col = wx * 64 + ni * 16 + l16;
        float bc = bias[col];
#pragma unroll
        for (int reg = 0; reg < 4; ++reg)
          T[(ni * 16 + l16) * 40 + mi * 16 + quad * 4 + reg] =
              f2b(acc[mi][ni][reg] + bc);
      }
    short* dst = &vT[((size_t)z * 64 + lane) * 1024 + (rb & 1023) + wy * 32];
#pragma unroll
    for (int c = 0; c < 4; ++c)
      *(uint4*)&dst[c * 8] = *(const uint4*)&T[lane * 40 + c * 8];
  }
#undef QKV_STAGE
}

// ---------- flash attention, S^T/O^T form, KV-split.
// 1-D grid 512, XCD swizzle, qt-fast: all 32 readers of a z's K/V on one XCD.
// K double-buffered; V SINGLE-buffered. 52KB -> 3 blocks/CU.
__global__ __launch_bounds__(256, 3) void attn_mfma(
    const short* __restrict__ q, const short* __restrict__ k,
    const short* __restrict__ vT, const int* __restrict__ mask,
    short* __restrict__ attnb, int cross) {
  __shared__ short Ks[2][2][4096];   // [buf][wv][64 keys x 64 dims]  32KB
  __shared__ short Vs[2][4096];      // [wv][64 dims x 64 keys]       16KB
  __shared__ float Msk[1024];        //                                4KB
  const int tid = threadIdx.x;
  const int lane = tid & 63, w = tid >> 6;
  const int wv = w & 1, wq = w >> 1;
  const int quad = lane >> 4, l16 = lane & 15;
  const int lr = lane >> 3;
  const int lcs = (((lane & 7) ^ lr) & 7) * 8;
  const int bid = blockIdx.x;
  const int swz = (bid & 7) * 64 + (bid >> 3);   // 512/8 = 64
  const int qt = swz & 31;
  const int z = swz >> 5;
  const int sb = z >> 2, h = z & 3;
  const int s = sb >> 1, b = sb & 1;
  const int rowbase = sb * 1024;
  const int* mp = mask + (b * 2 + (s ^ cross)) * 1024;

  const int qrow = qt * 32 + wq * 16 + l16;      // this lane's query
  bf16x8 qf[2];
#pragma unroll
  for (int kk = 0; kk < 2; ++kk)
    qf[kk] = *(const bf16x8*)&q[(size_t)(rowbase + qrow) * 256 + h * 64 + kk * 32 + quad * 8];

  {  // mask -> LDS bias, once
    int4 mv = *(const int4*)&mp[tid * 4];
    Msk[tid * 4 + 0] = (mv.x == 0) ? -1.0e9f : 0.f;
    Msk[tid * 4 + 1] = (mv.y == 0) ? -1.0e9f : 0.f;
    Msk[tid * 4 + 2] = (mv.z == 0) ? -1.0e9f : 0.f;
    Msk[tid * 4 + 3] = (mv.w == 0) ? -1.0e9f : 0.f;
  }

  const floatx4 z4 = {0.f, 0.f, 0.f, 0.f};
  floatx4 o4[4] = {z4, z4, z4, z4};
  float mrun = -1e30f, lsum = 0.f;

#define ATT_STAGE_K(t, buf)                                                             \
  {                                                                                     \
    int key0s = wv * 512 + (t) * 64;                                                    \
    _Pragma("unroll") for (int j = 0; j < 4; ++j)                                       \
      gl2lds16(&k[(size_t)(rowbase + key0s + j * 16 + wq * 8 + lr) * 256 + h * 64 + lcs], \
               &Ks[buf][wv][(j * 16 + wq * 8) * 64]);                                   \
  }
#define ATT_STAGE_V(t)                                                                  \
  {                                                                                     \
    int key0s = wv * 512 + (t) * 64;                                                    \
    _Pragma("unroll") for (int j = 0; j < 4; ++j)                                       \
      gl2lds16(&vT[((size_t)z * 64 + j * 16 + wq * 8 + lr) * 1024 + key0s + lcs],       \
               &Vs[wv][(j * 16 + wq * 8) * 64]);                                        \
  }

  ATT_STAGE_K(0, 0);
  ATT_STAGE_V(0);
  __syncthreads();     // drains all prologue stages + publishes Msk
  for (int t = 0; t < 8; ++t) {
    int buf = t & 1;
    // issue next K; wait own K(t) parts (8 younger allowed: V(t)+K(t+1))
    if (t < 7) { ATT_STAGE_K(t + 1, buf ^ 1); WAITV8; } else { WAITV4; }
    BARW;                                // K(t) visible block-wide
    const int key0 = wv * 512 + t * 64;

    // S^T tiles: A=K-frag (m=key), B=Q-frag (n=query)
    floatx4 sA[4] = {z4, z4, z4, z4};
    PRIO1;
#pragma unroll
    for (int kk = 0; kk < 2; ++kk) {
      const int sw = (((kk * 4 + quad) ^ (l16 & 7)) * 8);
#pragma unroll
      for (int mt = 0; mt < 4; ++mt) {
        bf16x8 kf = *(const bf16x8*)&Ks[buf][wv][(mt * 16 + l16) * 64 + sw];
        sA[mt] = __builtin_amdgcn_mfma_f32_16x16x32_bf16(kf, qf[kk], sA[mt], 0, 0, 0);
      }
    }
    PRIO0;
    float scv[4][4];
    float tmax = -1e30f;
#pragma unroll
    for (int mt = 0; mt < 4; ++mt) {
      float4 mk = *(const float4*)&Msk[key0 + mt * 16 + quad * 4];
      scv[mt][0] = sA[mt][0] * 0.125f + mk.x;
      scv[mt][1] = sA[mt][1] * 0.125f + mk.y;
      scv[mt][2] = sA[mt][2] * 0.125f + mk.z;
      scv[mt][3] = sA[mt][3] * 0.125f + mk.w;
#pragma unroll
      for (int reg = 0; reg < 4; ++reg) tmax = fmaxf(tmax, scv[mt][reg]);
    }
    tmax = fmaxf(tmax, __shfl_xor(tmax, 16));
    tmax = fmaxf(tmax, __shfl_xor(tmax, 32));
    float mnew = fmaxf(mrun, tmax);
    float corr = __expf(mrun - mnew);
    mrun = mnew;
    lsum *= corr;
#pragma unroll
    for (int dt = 0; dt < 4; ++dt)
#pragma unroll
      for (int reg = 0; reg < 4; ++reg) o4[dt][reg] *= corr;

    bf16x4 pb[4];
#pragma unroll
    for (int mt = 0; mt < 4; ++mt) {
      float e0 = __expf(scv[mt][0] - mnew);
      float e1 = __expf(scv[mt][1] - mnew);
      float e2 = __expf(scv[mt][2] - mnew);
      float e3 = __expf(scv[mt][3] - mnew);
      lsum += (e0 + e1) + (e2 + e3);
      union { bf16x4 v; uint2 u; } pu;
      pu.u.x = pack2(e0, e1); pu.u.y = pack2(e2, e3);
      pb[mt] = pu.v;
    }
    // V(t) ready: own parts via vmcnt, cross-wave via barrier
    if (t < 7) { WAITV4; } else { WAITV0; }
    BARW;
    // O^T += V^T @ P^T  (P^T straight from registers)
    PRIO1;
#pragma unroll
    for (int mt = 0; mt < 4; ++mt) {
      const int c2 = mt * 2 + (quad >> 1);
      const int sub = (quad & 1) * 4;
#pragma unroll
      for (int dt = 0; dt < 4; ++dt) {
        bf16x4 vf = *(const bf16x4*)&Vs[wv][(dt * 16 + l16) * 64 +
                                            ((c2 ^ (l16 & 7)) * 8) + sub];
        o4[dt] = mfma16_bf16(vf, pb[mt], o4[dt]);
      }
    }
    PRIO0;
    LGKM0;
    BARW;                 // all PV reads of Vs done -> safe to overwrite
    if (t < 7) ATT_STAGE_V(t + 1);
  }
  lsum += __shfl_xor(lsum, 16);
  lsum += __shfl_xor(lsum, 32);

  // merge the two KV halves via LDS (reuse Ks as fp32 scratch)
  float* MG = (float*)&Ks[0][0][0];
  const int mo = (wq * 64 + lane) * 18;
  if (wv == 1) {
    MG[mo] = mrun;
    MG[mo + 1] = lsum;
#pragma unroll
    for (int dt = 0; dt < 4; ++dt)
#pragma unroll
      for (int reg = 0; reg < 4; ++reg) MG[mo + 2 + dt * 4 + reg] = o4[dt][reg];
  }
  __syncthreads();
  if (wv == 0) {
    float m2 = MG[mo], l2 = MG[mo + 1];
    float mm = fmaxf(mrun, m2);
    float ca = __expf(mrun - mm), cb2 = __expf(m2 - mm);
    float inv = 1.f / (ca * lsum + cb2 * l2);
    short* op = &attnb[(size_t)(rowbase + qrow) * 256 + h * 64 + quad * 4];
#pragma unroll
    for (int dt = 0; dt < 4; ++dt) {
      float v0 = (ca * o4[dt][0] + cb2 * MG[mo + 2 + dt * 4 + 0]) * inv;
      float v1 = (ca * o4[dt][1] + cb2 * MG[mo + 2 + dt * 4 + 1]) * inv;
      float v2 = (ca * o4[dt][2] + cb2 * MG[mo + 2 + dt * 4 + 2]) * inv;
      float v3 = (ca * o4[dt][3] + cb2 * MG[mo + 2 + dt * 4 + 3]) * inv;
      uint2 uu;
      uu.x = pack2(v0, v1);
      uu.y = pack2(v2, v3);
      *(uint2*)&op[dt * 16] = uu;
    }
  }
#undef ATT_STAGE_K
#undef ATT_STAGE_V
}

// ---------- W1 GEMM (concat [x | attn]) + BN partial atomics.
// BM=64, 1-D grid 256, XCD swizzle, cb-fast. 2-deep counted-vmcnt, 8 k-steps.
// LDS 48KB + Ps 4KB = 52KB -> 3 blocks/CU.
__global__ __launch_bounds__(256, 3) void gemm_w1(
    const short* __restrict__ xb, const short* __restrict__ attnb,
    const short* __restrict__ w1t, const float* __restrict__ beff,
    float* __restrict__ hbuf, float* __restrict__ psumL, float* __restrict__ psqL) {
  __shared__ short SM[2 * 4096 + 2 * 8192];   // As[2][4096] | Bs[2][8192]
  __shared__ float Ps[2][2][128];
  short* As = SM;
  short* Bs = SM + 8192;
  const int bid = blockIdx.x;
  const int swz = (bid & 7) * 32 + (bid >> 3);   // 256/8 = 32
  const int rb = (swz >> 2) * 64, cb = (swz & 3) * 128;
  const int str = rb >> 11;      // stream for BN stats
  GEMM_IDS;
  floatx4 acc[2][4] = {{z4, z4, z4, z4}, {z4, z4, z4, z4}};

#define W1_STAGE(s, buf)                                                            \
  {                                                                                 \
    int k0 = (s) * 64;                                                              \
    const short* Ap = ((s) < 4 ? xb : attnb) + (size_t)rb * 256;                    \
    int kb = k0 & 255;                                                              \
    gl2lds16(&Ap[(size_t)(w * 8 + lr) * 256 + kb + lcs], &As[(buf) * 4096 + (w * 8) * 64]); \
    gl2lds16(&Ap[(size_t)(32 + w * 8 + lr) * 256 + kb + lcs], &As[(buf) * 4096 + (32 + w * 8) * 64]); \
    _Pragma("unroll") for (int i = 0; i < 4; ++i)                                   \
      gl2lds16(&w1t[(size_t)(cb + i * 32 + w * 8 + lr) * 512 + k0 + lcs],           \
               &Bs[(buf) * 8192 + (i * 32 + w * 8) * 64]);                          \
  }

  W1_STAGE(0, 0);
  W1_STAGE(1, 1);
  for (int s = 0; s < 8; ++s) {
    int buf = s & 1;
    if (s < 7) { WAITV6; } else { WAITV0; }
    BARW;
    mfma_step_sw(&As[buf * 4096], &Bs[buf * 8192], wy, wx, quad, l16, acc);
    BARW;
    if (s < 6) W1_STAGE(s + 2, buf);
  }
  float colsum[4], colsq[4];
#pragma unroll
  for (int ni = 0; ni < 4; ++ni) { colsum[ni] = 0.f; colsq[ni] = 0.f; }
#pragma unroll
  for (int mi = 0; mi < 2; ++mi)
#pragma unroll
    for (int ni = 0; ni < 4; ++ni) {
      int col = wx * 64 + ni * 16 + l16;
      float bc = beff[cb + col];
#pragma unroll
      for (int reg = 0; reg < 4; ++reg) {
        int row = rb + wy * 32 + mi * 16 + quad * 4 + reg;
        float val = acc[mi][ni][reg] + bc;
        hbuf[(size_t)row * 512 + cb + col] = val;
        colsum[ni] += val; colsq[ni] += val * val;
      }
    }
#pragma unroll
  for (int ni = 0; ni < 4; ++ni)
#pragma unroll
    for (int d = 16; d < 64; d <<= 1) {
      colsum[ni] += __shfl_xor(colsum[ni], d);
      colsq[ni]  += __shfl_xor(colsq[ni], d);
    }
  if (quad == 0) {
#pragma unroll
    for (int ni = 0; ni < 4; ++ni) {
      Ps[wy][0][wx * 64 + ni * 16 + l16] = colsum[ni];
      Ps[wy][1][wx * 64 + ni * 16 + l16] = colsq[ni];
    }
  }
  __syncthreads();
  if (tid < 128) {
    atomicAdd(&psumL[str * 512 + cb + tid], Ps[0][0][tid] + Ps[1][0][tid]);
    atomicAdd(&psqL [str * 512 + cb + tid], Ps[0][1][tid] + Ps[1][1][tid]);
  }
#undef W1_STAGE
}

// ---------- W2: BN finalize + fused BN/ReLU A-staging + residual.
// BM=64, 1-D grid 256, XCD swizzle. Counted-vmcnt 2-deep (A 4 + B 2 loads ->
// vmcnt(6)). LDS 32KB + 4KB BN = 36KB -> 4 blocks/CU.
__global__ __launch_bounds__(256, 4) void gemm_w2(
    const float* __restrict__ hbuf, const short* __restrict__ w2t,
    const float* __restrict__ b2_, const float* __restrict__ psumL,
    const float* __restrict__ psqL, const float* __restrict__ g,
    const float* __restrict__ be, float* __restrict__ xd, short* __restrict__ xb,
    float* __restrict__ outp) {
  __shared__ short SM[2 * 4096 + 2 * 4096];   // As[2][4096] | Bs[2][4096]
  __shared__ float s_scale[512], s_shift[512];
  short* As = SM;
  short* Bs = SM + 8192;
  const int bid = blockIdx.x;
  const int swz = (bid & 7) * 32 + (bid >> 3);   // 256/8 = 32
  const int rb = (swz >> 2) * 64, cb = (swz & 3) * 64;
  const int str = rb >> 11;
  GEMM_IDS;
  floatx4 acc[2][2] = {{z4, z4}, {z4, z4}};
#pragma unroll
  for (int cc = 0; cc < 2; ++cc) {
    int c = tid + cc * 256;
    float sum = psumL[str * 512 + c];
    float sq  = psqL [str * 512 + c];
    float mean = sum * (1.f / 2048.f);
    float var = sq * (1.f / 2048.f) - mean * mean;
    float rstd = rsqrtf(var + 1e-5f);
    float gs = g[c] * rstd;
    s_scale[c] = gs;
    s_shift[c] = be[c] - mean * gs;
  }
  __syncthreads();

  const int p = tid & 7, ar = tid >> 3;   // ar 0..31
  float4 ra0, ra1, ra2, ra3;

#define W2_A_LOAD(s)                                                               \
  {                                                                                \
    int k0 = (s) * 64;                                                             \
    int cs0 = k0 + ((p ^ (ar & 7)) * 8);                                           \
    int cs1 = k0 + ((p ^ ((ar + 32) & 7)) * 8);                                    \
    ra0 = *(const float4*)&hbuf[(size_t)(rb + ar) * 512 + cs0];                    \
    ra1 = *(const float4*)&hbuf[(size_t)(rb + ar) * 512 + cs0 + 4];                \
    ra2 = *(const float4*)&hbuf[(size_t)(rb + 32 + ar) * 512 + cs1];               \
    ra3 = *(const float4*)&hbuf[(size_t)(rb + 32 + ar) * 512 + cs1 + 4];           \
  }
#define W2_A_WRITE(s, buf)                                                         \
  {                                                                                \
    int k0 = (s) * 64;                                                             \
    int cs0 = k0 + ((p ^ (ar & 7)) * 8);                                           \
    int cs1 = k0 + ((p ^ ((ar + 32) & 7)) * 8);                                    \
    float4 sc0 = *(const float4*)&s_scale[cs0];                                    \
    float4 sc1 = *(const float4*)&s_scale[cs0 + 4];                                \
    float4 sh0 = *(const float4*)&s_shift[cs0];                                    \
    float4 sh1 = *(const float4*)&s_shift[cs0 + 4];                                \
    uint4 pk;                                                                      \
    pk.x = pack2(fmaxf(ra0.x * sc0.x + sh0.x, 0.f), fmaxf(ra0.y * sc0.y + sh0.y, 0.f)); \
    pk.y = pack2(fmaxf(ra0.z * sc0.z + sh0.z, 0.f), fmaxf(ra0.w * sc0.w + sh0.w, 0.f)); \
    pk.z = pack2(fmaxf(ra1.x * sc1.x + sh1.x, 0.f), fmaxf(ra1.y * sc1.y + sh1.y, 0.f)); \
    pk.w = pack2(fmaxf(ra1.z * sc1.z + sh1.z, 0.f), fmaxf(ra1.w * sc1.w + sh1.w, 0.f)); \
    *(uint4*)&As[(buf) * 4096 + ar * 64 + p * 8] = pk;                             \
    float4 sc2 = *(const float4*)&s_scale[cs1];                                    \
    float4 sc3 = *(const float4*)&s_scale[cs1 + 4];                                \
    float4 sh2 = *(const float4*)&s_shift[cs1];                                    \
    float4 sh3 = *(const float4*)&s_shift[cs1 + 4];                                \
    pk.x = pack2(fmaxf(ra2.x * sc2.x + sh2.x, 0.f), fmaxf(ra2.y * sc2.y + sh2.y, 0.f)); \
    pk.y = pack2(fmaxf(ra2.z * sc2.z + sh2.z, 0.f), fmaxf(ra2.w * sc2.w + sh2.w, 0.f)); \
    pk.z = pack2(fmaxf(ra3.x * sc3.x + sh3.x, 0.f), fmaxf(ra3.y * sc3.y + sh3.y, 0.f)); \
    pk.w = pack2(fmaxf(ra3.z * sc3.z + sh3.z, 0.f), fmaxf(ra3.w * sc3.w + sh3.w, 0.f)); \
    *(uint4*)&As[(buf) * 4096 + (32 + ar) * 64 + p * 8] = pk;                      \
  }
#define W2_STAGE_B(s, buf)                                                         \
  {                                                                                \
    int k0 = (s) * 64;                                                             \
    _Pragma("unroll") for (int i = 0; i < 2; ++i)                                  \
      gl2lds16(&w2t[(size_t)(cb + i * 32 + w * 8 + lr) * 512 + k0 + lcs],          \
               &Bs[(buf) * 4096 + (i * 32 + w * 8) * 64]);                         \
  }

  W2_A_LOAD(0);
  W2_STAGE_B(0, 0);
  W2_A_WRITE(0, 0);
  LGKM0;
  for (int s = 0; s < 8; ++s) {
    int buf = s & 1;
    if (s < 7) { W2_A_LOAD(s + 1); W2_STAGE_B(s + 1, buf ^ 1); WAITV6; } else { WAITV0; }
    BARW;
    mfma_step_sw64(&As[buf * 4096], &Bs[buf * 4096], wy, wx, quad, l16, acc);
    if (s < 7) W2_A_WRITE(s + 1, buf ^ 1);
    LGKM0;
    BARW;
  }
#pragma unroll
  for (int mi = 0; mi < 2; ++mi)
#pragma unroll
    for (int ni = 0; ni < 2; ++ni) {
      int col = cb + wx * 32 + ni * 16 + l16;
      float bc = b2_[col];
#pragma unroll
      for (int reg = 0; reg < 4; ++reg) {
        int row = rb + wy * 32 + mi * 16 + quad * 4 + reg;
        float r = xd[(size_t)row * 256 + col] + acc[mi][ni][reg] + bc;
        xd[(size_t)row * 256 + col] = r;
        xb[(size_t)row * 256 + col] = f2b(r);
        if (outp) {
          int ss = row >> 11, bb = (row >> 10) & 1, n = row & 1023;
          outp[(size_t)((bb * 2 + ss) * 1024 + n) * 256 + col] = r;
        }
      }
    }
#undef W2_A_LOAD
#undef W2_A_WRITE
#undef W2_STAGE_B
}

extern "C" void kernel_launch(void* const* d_in, const int* in_sizes, int n_in,
                              void* d_out, int out_size, void* d_ws, size_t ws_size,
                              hipStream_t stream) {
  (void)in_sizes; (void)n_in; (void)out_size; (void)ws_size;
  const float* desc = (const float*)d_in[0];
  const int*   mask = (const int*)d_in[1];
  const float* qw = (const float*)d_in[2];
  const float* qb = (const float*)d_in[3];
  const float* kw = (const float*)d_in[4];
  const float* kb = (const float*)d_in[5];
  const float* vw = (const float*)d_in[6];
  const float* vb = (const float*)d_in[7];
  const float* ow = (const float*)d_in[8];
  const float* ob = (const float*)d_in[9];
  const float* w1 = (const float*)d_in[10];
  const float* b1 = (const float*)d_in[11];
  const float* bn_g = (const float*)d_in[12];
  const float* bn_b = (const float*)d_in[13];
  const float* w2 = (const float*)d_in[14];
  const float* b2 = (const float*)d_in[15];
  float* out = (float*)d_out;

  char* base = (char*)d_ws;
  float* xd    = (float*)(base);                  // [0,4) MB
  float* hbuf  = (float*)(base + (4u << 20));     // [4,12) MB
  short* xb    = (short*)(base + (12u << 20));
  short* qb16  = (short*)(base + (14u << 20));
  short* kb16  = (short*)(base + (16u << 20));
  short* vTb   = (short*)(base + (18u << 20));
  short* attnb = (short*)(base + (20u << 20));
  float* psum  = (float*)(base + (22u << 20));    // [18][2][512]
  float* psq   = psum + 18 * 1024;                // [18][2][512]
  float* beff  = psq + 18 * 1024;                 // 18*512 fp32
  short* wbuf  = (short*)(base + (24u << 20));    // 18*655360 shorts = 23.6 MB

  wprep<<<3796, 256, 0, stream>>>(qw, kw, vw, w1, w2, ob, b1,
                                  wbuf, beff, desc, xd, xb, psum);
  wfuse<<<288, 256, 0, stream>>>(ow, w1, wbuf);

  for (int i = 0; i < 18; ++i) {
    int cross = i & 1;
    short* wb = wbuf + (size_t)i * 655360;

    gemm_qkv<<<384, 256, 0, stream>>>(
        xb, wb, qb + (size_t)i * 256, kb + (size_t)i * 256, vb + (size_t)i * 256,
        qb16, kb16, vTb, cross);
    attn_mfma<<<512, 256, 0, stream>>>(qb16, kb16, vTb, mask, attnb, cross);
    gemm_w1<<<256, 256, 0, stream>>>(xb, attnb, wb + 262144,
                                     beff + (size_t)i * 512,
                                     hbuf, psum + (size_t)i * 1024,
                                     psq + (size_t)i * 1024);
    gemm_w2<<<256, 256, 0, stream>>>(hbuf, wb + 524288,
                                     b2 + (size_t)i * 256,
                                     psum + (size_t)i * 1024,
                                     psq + (size_t)i * 1024,
                                     bn_g + (size_t)i * 512,
                                     bn_b + (size_t)i * 512, xd, xb,
                                     (i == 17) ? out : nullptr);
  }
}

// Round 11
// 864.755 us; speedup vs baseline: 1.0860x; 1.0860x over previous
//
#include <hip/hip_runtime.h>

// B=2, streams=2, N=1024, D=256, H=4, DH=64, L=18
// Row layout: r = s*2048 + b*1024 + n  (M=4096 rows)
// bf16 MFMA 16x16x32: A-frag lane=A[m=lane&15][k=quad*8+j]; B-frag B[k=quad*8+j][n=lane&15]
// C/D: col=lane&15, row=quad*4+reg
// LDS XOR swizzle: 16B chunk c of row r stored at slot (c ^ (r&7)).
// BN stats PER STREAM (2048 rows each), accumulated via global fp32 atomics.
// R10->R11: REVERT loop kernels to R9 (BM=32, grids 768/512/512/512; BM=64 lost
//   56us: grid<2x CU re-exposes latency). wprep: drop the 576 wasted w1-bottom
//   wconv blocks (wfuse overwrites that range) and absorb wfuse as a tail
//   block-range of wprep (one dispatch, compute/memory overlap, no write overlap).
// NOTE (R5 lesson): persistent kernel + homemade grid barrier = ~69us/barrier on
// CDNA4; kernel boundaries (~4us) are the cheap sync.

typedef __attribute__((ext_vector_type(8))) short bf16x8;
typedef __attribute__((ext_vector_type(4))) short bf16x4;
typedef __attribute__((ext_vector_type(4))) float floatx4;

__device__ __forceinline__ short f2b(float f) {   // fp32 -> bf16 RNE
  unsigned u = __builtin_bit_cast(unsigned, f);
  unsigned r = (u + 0x7FFFu + ((u >> 16) & 1u)) >> 16;
  return (short)r;
}
__device__ __forceinline__ unsigned pack2(float a, float b) {
  return (unsigned)(unsigned short)f2b(a) | ((unsigned)(unsigned short)f2b(b) << 16);
}
// split a,b into bf16-hi pair (packed) and fp32-residual bf16 pair (packed)
__device__ __forceinline__ void split2(float a, float b, unsigned& h, unsigned& l) {
  unsigned short ha = (unsigned short)f2b(a), hb = (unsigned short)f2b(b);
  float fa = __builtin_bit_cast(float, (unsigned)ha << 16);
  float fb = __builtin_bit_cast(float, (unsigned)hb << 16);
  h = (unsigned)ha | ((unsigned)hb << 16);
  l = pack2(a - fa, b - fb);
}

__device__ __forceinline__ void gl2lds16(const void* g, void* l) {
  __builtin_amdgcn_global_load_lds(
      (const __attribute__((address_space(1))) unsigned*)g,
      (__attribute__((address_space(3))) unsigned*)l, 16, 0, 0);
}

__device__ __forceinline__ floatx4 mfma16_bf16(bf16x4 a, bf16x4 b, floatx4 c) {
#if __has_builtin(__builtin_amdgcn_mfma_f32_16x16x16_bf16)
  return __builtin_amdgcn_mfma_f32_16x16x16_bf16(a, b, c, 0, 0, 0);
#elif __has_builtin(__builtin_amdgcn_mfma_f32_16x16x16bf16_1k)
  return __builtin_amdgcn_mfma_f32_16x16x16bf16_1k(a, b, c, 0, 0, 0);
#else
  asm volatile("v_mfma_f32_16x16x16_bf16 %0, %1, %2, %0" : "+v"(c) : "v"(a), "v"(b));
  return c;
#endif
}

#define BARW   asm volatile("s_barrier" ::: "memory")
#define WAITV8 asm volatile("s_waitcnt vmcnt(8)" ::: "memory")
#define WAITV5 asm volatile("s_waitcnt vmcnt(5)" ::: "memory")
#define WAITV4 asm volatile("s_waitcnt vmcnt(4)" ::: "memory")
#define WAITV0 asm volatile("s_waitcnt vmcnt(0)" ::: "memory")
#define LGKM0  asm volatile("s_waitcnt lgkmcnt(0)" ::: "memory")
#define PRIO1  __builtin_amdgcn_s_setprio(1)
#define PRIO0  __builtin_amdgcn_s_setprio(0)

#define GEMM_IDS                                        \
  const int tid = threadIdx.x;                          \
  const int lane = tid & 63, w = tid >> 6;              \
  const int wy = w >> 1, wx = w & 1;                    \
  const int quad = lane >> 4, l16 = lane & 15;          \
  const int lr = lane >> 3;                             \
  const int lcs = (((lane & 7) ^ lr) & 7) * 8;          \
  const floatx4 z4 = {0.f, 0.f, 0.f, 0.f};

// swizzled MFMA K-step (BM=64, BN=128, wave-tile 32x64) -- used by wfuse branch
__device__ __forceinline__ void mfma_step_sw(const short* As, const short* Bs,
                                             int wy, int wx, int quad, int l16,
                                             floatx4 acc[2][4]) {
#pragma unroll
  for (int kk = 0; kk < 2; ++kk) {
    const int sw = (((kk * 4 + quad) ^ (l16 & 7)) * 8);
    bf16x8 a0 = *(const bf16x8*)&As[(wy * 32 + l16) * 64 + sw];
    bf16x8 a1 = *(const bf16x8*)&As[(wy * 32 + 16 + l16) * 64 + sw];
    bf16x8 b[4];
#pragma unroll
    for (int ni = 0; ni < 4; ++ni)
      b[ni] = *(const bf16x8*)&Bs[(wx * 64 + ni * 16 + l16) * 64 + sw];
#pragma unroll
    for (int ni = 0; ni < 4; ++ni) {
      acc[0][ni] = __builtin_amdgcn_mfma_f32_16x16x32_bf16(a0, b[ni], acc[0][ni], 0, 0, 0);
      acc[1][ni] = __builtin_amdgcn_mfma_f32_16x16x32_bf16(a1, b[ni], acc[1][ni], 0, 0, 0);
    }
  }
}

// swizzled MFMA K-step (BM=32, BN=128, wave-tile 16x64)
__device__ __forceinline__ void mfma_step_sw32(const short* As, const short* Bs,
                                               int wy, int wx, int quad, int l16,
                                               floatx4 acc[4]) {
#pragma unroll
  for (int kk = 0; kk < 2; ++kk) {
    const int sw = (((kk * 4 + quad) ^ (l16 & 7)) * 8);
    bf16x8 a0 = *(const bf16x8*)&As[(wy * 16 + l16) * 64 + sw];
    bf16x8 b[4];
#pragma unroll
    for (int ni = 0; ni < 4; ++ni)
      b[ni] = *(const bf16x8*)&Bs[(wx * 64 + ni * 16 + l16) * 64 + sw];
#pragma unroll
    for (int ni = 0; ni < 4; ++ni)
      acc[ni] = __builtin_amdgcn_mfma_f32_16x16x32_bf16(a0, b[ni], acc[ni], 0, 0, 0);
  }
}

// swizzled MFMA K-step (BM=32, BN=64, wave-tile 16x32)
__device__ __forceinline__ void mfma_step_sw32x64(const short* As, const short* Bs,
                                                  int wy, int wx, int quad, int l16,
                                                  floatx4 acc[2]) {
#pragma unroll
  for (int kk = 0; kk < 2; ++kk) {
    const int sw = (((kk * 4 + quad) ^ (l16 & 7)) * 8);
    bf16x8 a0 = *(const bf16x8*)&As[(wy * 16 + l16) * 64 + sw];
    bf16x8 b[2];
#pragma unroll
    for (int ni = 0; ni < 2; ++ni)
      b[ni] = *(const bf16x8*)&Bs[(wx * 32 + ni * 16 + l16) * 64 + sw];
#pragma unroll
    for (int ni = 0; ni < 2; ++ni)
      acc[ni] = __builtin_amdgcn_mfma_f32_16x16x32_bf16(a0, b[ni], acc[ni], 0, 0, 0);
  }
}

// ---------- prep kernel (wfuse absorbed):
// blocks [0,2016): wconv transpose+convert, 32k x 128n tiles (qkv + w1-TOP + w2)
// blocks [2016,2160): bfuse
// blocks [2160,3184): input swap-copy
// blocks [3184,3220): zero psum/psq
// blocks [3220,3508): wfuse  F = ow @ w1bot; F^T -> w1t[n][256+kp]
__global__ __launch_bounds__(256) void wprep(
    const float* __restrict__ qw, const float* __restrict__ kw,
    const float* __restrict__ vw, const float* __restrict__ ow,
    const float* __restrict__ w1, const float* __restrict__ w2,
    const float* __restrict__ ob, const float* __restrict__ b1,
    short* __restrict__ wbuf, float* __restrict__ beff,
    const float* __restrict__ desc, float* __restrict__ xd,
    short* __restrict__ xb, float* __restrict__ psz) {
  __shared__ __align__(16) char SMU[49152];   // union: SH (16.6KB) | wfuse bufs (48KB)
  float* SH = (float*)SMU;
  int blk = blockIdx.x;
  int t = threadIdx.x;
  if (blk < 2016) {
    // ---- wconv: coalesced loads -> padded LDS -> transposed bf16 (w1 TOP only)
    int layer = blk / 112;
    int sub2 = blk % 112;
    int sub = sub2 >> 1;          // 0..55
    int khalf = sub2 & 1;         // 32-row half of the 64-row tile
    const float* W; int Kd, Nd, k0, n0; size_t ooff;
    if (sub < 24) {
      int wsel = sub / 8; int tt = sub & 7;
      k0 = (tt >> 1) * 64; n0 = (tt & 1) * 128; Kd = 256; Nd = 256;
      W = (wsel == 0 ? qw : wsel == 1 ? kw : vw) + (size_t)layer * 65536;
      ooff = (size_t)wsel * 65536;
    } else if (sub < 40) {
      int tt = sub - 24;          // 16 tiles: K rows [0,256) of w1 only
      k0 = (tt >> 2) * 64; n0 = (tt & 3) * 128;
      Kd = 512; Nd = 512; W = w1 + (size_t)layer * 262144; ooff = 262144;
    } else {
      int tt = sub - 40; k0 = (tt >> 1) * 64; n0 = (tt & 1) * 128;
      Kd = 512; Nd = 256; W = w2 + (size_t)layer * 131072; ooff = 524288;
    }
    k0 += khalf * 32;
    short* out = wbuf + (size_t)layer * 655360 + ooff;
    const int rr = t >> 4;          // 0..15
    const int c4 = (t & 15) * 4;
#pragma unroll
    for (int i = 0; i < 2; ++i)
#pragma unroll
      for (int hf = 0; hf < 2; ++hf) {
        float4 v = *(const float4*)&W[(size_t)(k0 + i * 16 + rr) * Nd + n0 + hf * 64 + c4];
        float* tp = &SH[(i * 16 + rr) * 130 + hf * 64 + c4];
        tp[0] = v.x; tp[1] = v.y; tp[2] = v.z; tp[3] = v.w;
      }
    __syncthreads();
    const int n = t >> 1;           // 0..127 col within tile
    const int kh = (t & 1) * 16;    // 16-k half of the 32 rows
    float v[16];
#pragma unroll
    for (int kk = 0; kk < 16; ++kk)
      v[kk] = SH[(kh + kk) * 130 + n];
    unsigned u[8];
#pragma unroll
    for (int j2 = 0; j2 < 8; ++j2) u[j2] = pack2(v[2 * j2], v[2 * j2 + 1]);
    short* op = &out[(size_t)(n0 + n) * Kd + k0 + kh];
    uint4 o1; o1.x = u[0]; o1.y = u[1]; o1.z = u[2]; o1.w = u[3];
    uint4 o2; o2.x = u[4]; o2.y = u[5]; o2.z = u[6]; o2.w = u[7];
    *(uint4*)&op[0] = o1;
    *(uint4*)&op[8] = o2;
  } else if (blk < 2160) {
    // ---- bfuse: beff[l][n] = b1[l][n] + sum_i ob[l][i]*w1[l][256+i][n]
    int bb = blk - 2016;
    int layer = bb >> 3;
    int n0 = (bb & 7) * 64;
    const float* obL = ob + (size_t)layer * 256;
    const float* w1L = w1 + (size_t)layer * 262144 + 256 * 512;
    int n = n0 + (t & 63);
    int part = t >> 6;
    float s = 0.f;
    for (int i = part * 64; i < part * 64 + 64; ++i)
      s += obL[i] * w1L[(size_t)i * 512 + n];
    SH[part * 64 + (t & 63)] = s;
    __syncthreads();
    if (t < 64) {
      float tot = SH[t] + SH[64 + t] + SH[128 + t] + SH[192 + t] +
                  b1[(size_t)layer * 512 + n0 + t];
      beff[(size_t)layer * 512 + n0 + t] = tot;
    }
  } else if (blk < 3184) {
    // ---- input copy with (s,b) swap
    int idx = (blk - 2160) * 256 + t;
    int fi = idx << 2;
    int hi = (fi >> 19) & 1;
    int lo = (fi >> 18) & 1;
    int sj = (fi & ~(3 << 18)) | (lo << 19) | (hi << 18);
    float4 v = *(const float4*)&desc[sj];
    *(float4*)&xd[fi] = v;
    uint2 uu; uu.x = pack2(v.x, v.y); uu.y = pack2(v.z, v.w);
    *(uint2*)&xb[fi] = uu;
  } else if (blk < 3220) {
    // ---- zero BN partial accumulators
    int idx = (blk - 3184) * 1024 + t * 4;
    float4 zz = {0.f, 0.f, 0.f, 0.f};
    *(float4*)&psz[idx] = zz;
  } else {
    // ---- wfuse: F = ow(256x256) @ w1bot(256x512), hi/lo 3-term MFMA split
    short* As_h = (short*)SMU;              // [64*64]
    short* As_l = As_h + 4096;              // [64*64]
    short* Bs_h = As_l + 4096;              // [128*64]
    short* Bs_l = Bs_h + 8192;              // [128*64]
    const int wblk = blk - 3220;
    const int layer = wblk >> 4, sub = wblk & 15;
    const int kp0 = (sub & 3) * 64, n0 = (sub >> 2) * 128;
    const float* A = ow + (size_t)layer * 65536;                 // [kp][i]
    const float* Bw = w1 + (size_t)layer * 262144 + 256 * 512;   // [i][n]
    short* w1t = wbuf + (size_t)layer * 655360 + 262144;
    const int lane = t & 63, w = t >> 6;
    const int wy = w >> 1, wx = w & 1;
    const int quad = lane >> 4, l16 = lane & 15;
    const floatx4 z4 = {0.f, 0.f, 0.f, 0.f};
    floatx4 acc[2][4] = {{z4, z4, z4, z4}, {z4, z4, z4, z4}};
    const int ar = t >> 2, aq = t & 3;
    const int bn = t & 127, bkh = t >> 7;

    for (int s = 0; s < 4; ++s) {
      const int k0 = s * 64;
      const float* Ar = &A[(size_t)(kp0 + ar) * 256 + k0 + aq * 16];
      float4 f0 = *(const float4*)&Ar[0];
      float4 f1 = *(const float4*)&Ar[4];
      float4 f2 = *(const float4*)&Ar[8];
      float4 f3 = *(const float4*)&Ar[12];
      float bv[32];
#pragma unroll
      for (int kk2 = 0; kk2 < 32; ++kk2)
        bv[kk2] = Bw[(size_t)(k0 + bkh * 32 + kk2) * 512 + n0 + bn];

      __syncthreads();
      {
        uint4 hi, lo;
        split2(f0.x, f0.y, hi.x, lo.x);
        split2(f0.z, f0.w, hi.y, lo.y);
        split2(f1.x, f1.y, hi.z, lo.z);
        split2(f1.z, f1.w, hi.w, lo.w);
        int sl = ((aq * 2) ^ (ar & 7)) * 8;
        *(uint4*)&As_h[ar * 64 + sl] = hi;
        *(uint4*)&As_l[ar * 64 + sl] = lo;
        split2(f2.x, f2.y, hi.x, lo.x);
        split2(f2.z, f2.w, hi.y, lo.y);
        split2(f3.x, f3.y, hi.z, lo.z);
        split2(f3.z, f3.w, hi.w, lo.w);
        sl = ((aq * 2 + 1) ^ (ar & 7)) * 8;
        *(uint4*)&As_h[ar * 64 + sl] = hi;
        *(uint4*)&As_l[ar * 64 + sl] = lo;
      }
#pragma unroll
      for (int cc = 0; cc < 4; ++cc) {
        uint4 hi, lo;
        split2(bv[cc * 8 + 0], bv[cc * 8 + 1], hi.x, lo.x);
        split2(bv[cc * 8 + 2], bv[cc * 8 + 3], hi.y, lo.y);
        split2(bv[cc * 8 + 4], bv[cc * 8 + 5], hi.z, lo.z);
        split2(bv[cc * 8 + 6], bv[cc * 8 + 7], hi.w, lo.w);
        int sl = ((bkh * 4 + cc) ^ (bn & 7)) * 8;
        *(uint4*)&Bs_h[bn * 64 + sl] = hi;
        *(uint4*)&Bs_l[bn * 64 + sl] = lo;
      }
      __syncthreads();
      mfma_step_sw(As_h, Bs_h, wy, wx, quad, l16, acc);
      mfma_step_sw(As_h, Bs_l, wy, wx, quad, l16, acc);
      mfma_step_sw(As_l, Bs_h, wy, wx, quad, l16, acc);
    }
#pragma unroll
    for (int mi = 0; mi < 2; ++mi)
#pragma unroll
      for (int ni = 0; ni < 4; ++ni) {
        int col = n0 + wx * 64 + ni * 16 + l16;             // n
        int row0 = kp0 + wy * 32 + mi * 16 + quad * 4;      // kp base
        uint2 uu;
        uu.x = pack2(acc[mi][ni][0], acc[mi][ni][1]);
        uu.y = pack2(acc[mi][ni][2], acc[mi][ni][3]);
        *(uint2*)&w1t[(size_t)col * 512 + 256 + row0] = uu;
      }
  }
}

// ---------- fused QKV GEMM: 1-D grid 768, XCD swizzle, cb-fast tile order.
// FULL K=256 resident: As[4][2048] + Bs[4][8192] = 80KB -> 2 blocks/CU.
__global__ __launch_bounds__(256, 2) void gemm_qkv(
    const short* __restrict__ xb, const short* __restrict__ wbufL,
    const float* __restrict__ qb_, const float* __restrict__ kb_,
    const float* __restrict__ vb_,
    short* __restrict__ q, short* __restrict__ kout, short* __restrict__ vT,
    int cross) {
  __shared__ short SM[40960];     // 80KB exactly
  short* As = SM;                 // [4][2048]
  short* Bs = SM + 8192;          // [4][8192]
  // XCD-locality: tiles with same rb (sharing A rows) contiguous per XCD
  const int bid = blockIdx.x;
  const int swz = (bid & 7) * 96 + (bid >> 3);   // 768/8 = 96
  const int rb = (swz / 6) * 32;
  const int cb = (swz % 6) * 128;
  const int seg = cb >> 8;
  const int cbl = cb & 255;
  int arb = rb;
  if (seg) arb = (rb & 2047) | ((((rb >> 11) ^ cross) & 1) << 11);
  const short* A = xb + (size_t)arb * 256;
  const short* Wt = wbufL + (size_t)seg * 65536 + (size_t)cbl * 256;
  const float* bias = (seg == 0 ? qb_ : seg == 1 ? kb_ : vb_) + cbl;
  GEMM_IDS;
  floatx4 acc[4] = {z4, z4, z4, z4};

#pragma unroll
  for (int s = 0; s < 4; ++s) {
    const int k0 = s * 64;
    gl2lds16(&A[(size_t)(w * 8 + lr) * 256 + k0 + lcs], &As[s * 2048 + (w * 8) * 64]);
#pragma unroll
    for (int i = 0; i < 4; ++i)
      gl2lds16(&Wt[(size_t)(i * 32 + w * 8 + lr) * 256 + k0 + lcs],
               &Bs[s * 8192 + (i * 32 + w * 8) * 64]);
  }
  WAITV0;
  BARW;
#pragma unroll
  for (int s = 0; s < 4; ++s)
    mfma_step_sw32(&As[s * 2048], &Bs[s * 8192], wy, wx, quad, l16, acc);

  if (seg < 2) {
    short* C = (seg == 0 ? q : kout) + (size_t)rb * 256 + cbl;
#pragma unroll
    for (int ni = 0; ni < 4; ++ni) {
      int col = wx * 64 + ni * 16 + l16;
      float bc = bias[col];
#pragma unroll
      for (int reg = 0; reg < 4; ++reg) {
        int row = wy * 16 + quad * 4 + reg;
        C[(size_t)row * 256 + col] = f2b(acc[ni][reg] + bc);
      }
    }
  } else {
    BARW;                              // all LDS reads done; reuse as scratch
    short* T = SM + w * 1536;          // 64 dims x 24 (pad), wave-local
    const int sb = rb >> 10;
    const int hh = (cbl >> 6) + wx;
    const int z = sb * 4 + hh;
#pragma unroll
    for (int ni = 0; ni < 4; ++ni) {
      int col = wx * 64 + ni * 16 + l16;
      float bc = bias[col];
#pragma unroll
      for (int reg = 0; reg < 4; ++reg)
        T[(ni * 16 + l16) * 24 + quad * 4 + reg] = f2b(acc[ni][reg] + bc);
    }
    short* dst = &vT[((size_t)z * 64 + lane) * 1024 + (rb & 1023) + wy * 16];
    *(uint4*)&dst[0] = *(const uint4*)&T[lane * 24 + 0];
    *(uint4*)&dst[8] = *(const uint4*)&T[lane * 24 + 8];
  }
}

// ---------- flash attention, S^T/O^T form, KV-split.
// 1-D grid 512, XCD swizzle, qt-fast: all 32 readers of a z's K/V on one XCD.
// K double-buffered; V SINGLE-buffered. 52KB -> 3 blocks/CU.
__global__ __launch_bounds__(256, 3) void attn_mfma(
    const short* __restrict__ q, const short* __restrict__ k,
    const short* __restrict__ vT, const int* __restrict__ mask,
    short* __restrict__ attnb, int cross) {
  __shared__ short Ks[2][2][4096];   // [buf][wv][64 keys x 64 dims]  32KB
  __shared__ short Vs[2][4096];      // [wv][64 dims x 64 keys]       16KB
  __shared__ float Msk[1024];        //                                4KB
  const int tid = threadIdx.x;
  const int lane = tid & 63, w = tid >> 6;
  const int wv = w & 1, wq = w >> 1;
  const int quad = lane >> 4, l16 = lane & 15;
  const int lr = lane >> 3;
  const int lcs = (((lane & 7) ^ lr) & 7) * 8;
  const int bid = blockIdx.x;
  const int swz = (bid & 7) * 64 + (bid >> 3);   // 512/8 = 64
  const int qt = swz & 31;
  const int z = swz >> 5;
  const int sb = z >> 2, h = z & 3;
  const int s = sb >> 1, b = sb & 1;
  const int rowbase = sb * 1024;
  const int* mp = mask + (b * 2 + (s ^ cross)) * 1024;

  const int qrow = qt * 32 + wq * 16 + l16;      // this lane's query
  bf16x8 qf[2];
#pragma unroll
  for (int kk = 0; kk < 2; ++kk)
    qf[kk] = *(const bf16x8*)&q[(size_t)(rowbase + qrow) * 256 + h * 64 + kk * 32 + quad * 8];

  {  // mask -> LDS bias, once
    int4 mv = *(const int4*)&mp[tid * 4];
    Msk[tid * 4 + 0] = (mv.x == 0) ? -1.0e9f : 0.f;
    Msk[tid * 4 + 1] = (mv.y == 0) ? -1.0e9f : 0.f;
    Msk[tid * 4 + 2] = (mv.z == 0) ? -1.0e9f : 0.f;
    Msk[tid * 4 + 3] = (mv.w == 0) ? -1.0e9f : 0.f;
  }

  const floatx4 z4 = {0.f, 0.f, 0.f, 0.f};
  floatx4 o4[4] = {z4, z4, z4, z4};
  float mrun = -1e30f, lsum = 0.f;

#define ATT_STAGE_K(t, buf)                                                             \
  {                                                                                     \
    int key0s = wv * 512 + (t) * 64;                                                    \
    _Pragma("unroll") for (int j = 0; j < 4; ++j)                                       \
      gl2lds16(&k[(size_t)(rowbase + key0s + j * 16 + wq * 8 + lr) * 256 + h * 64 + lcs], \
               &Ks[buf][wv][(j * 16 + wq * 8) * 64]);                                   \
  }
#define ATT_STAGE_V(t)                                                                  \
  {                                                                                     \
    int key0s = wv * 512 + (t) * 64;                                                    \
    _Pragma("unroll") for (int j = 0; j < 4; ++j)                                       \
      gl2lds16(&vT[((size_t)z * 64 + j * 16 + wq * 8 + lr) * 1024 + key0s + lcs],       \
               &Vs[wv][(j * 16 + wq * 8) * 64]);                                        \
  }

  ATT_STAGE_K(0, 0);
  ATT_STAGE_V(0);
  __syncthreads();     // drains all prologue stages + publishes Msk
  for (int t = 0; t < 8; ++t) {
    int buf = t & 1;
    // issue next K; wait own K(t) parts (8 younger allowed: V(t)+K(t+1))
    if (t < 7) { ATT_STAGE_K(t + 1, buf ^ 1); WAITV8; } else { WAITV4; }
    BARW;                                // K(t) visible block-wide
    const int key0 = wv * 512 + t * 64;

    // S^T tiles: A=K-frag (m=key), B=Q-frag (n=query)
    floatx4 sA[4] = {z4, z4, z4, z4};
    PRIO1;
#pragma unroll
    for (int kk = 0; kk < 2; ++kk) {
      const int sw = (((kk * 4 + quad) ^ (l16 & 7)) * 8);
#pragma unroll
      for (int mt = 0; mt < 4; ++mt) {
        bf16x8 kf = *(const bf16x8*)&Ks[buf][wv][(mt * 16 + l16) * 64 + sw];
        sA[mt] = __builtin_amdgcn_mfma_f32_16x16x32_bf16(kf, qf[kk], sA[mt], 0, 0, 0);
      }
    }
    PRIO0;
    float scv[4][4];
    float tmax = -1e30f;
#pragma unroll
    for (int mt = 0; mt < 4; ++mt) {
      float4 mk = *(const float4*)&Msk[key0 + mt * 16 + quad * 4];
      scv[mt][0] = sA[mt][0] * 0.125f + mk.x;
      scv[mt][1] = sA[mt][1] * 0.125f + mk.y;
      scv[mt][2] = sA[mt][2] * 0.125f + mk.z;
      scv[mt][3] = sA[mt][3] * 0.125f + mk.w;
#pragma unroll
      for (int reg = 0; reg < 4; ++reg) tmax = fmaxf(tmax, scv[mt][reg]);
    }
    tmax = fmaxf(tmax, __shfl_xor(tmax, 16));
    tmax = fmaxf(tmax, __shfl_xor(tmax, 32));
    float mnew = fmaxf(mrun, tmax);
    float corr = __expf(mrun - mnew);
    mrun = mnew;
    lsum *= corr;
#pragma unroll
    for (int dt = 0; dt < 4; ++dt)
#pragma unroll
      for (int reg = 0; reg < 4; ++reg) o4[dt][reg] *= corr;

    bf16x4 pb[4];
#pragma unroll
    for (int mt = 0; mt < 4; ++mt) {
      float e0 = __expf(scv[mt][0] - mnew);
      float e1 = __expf(scv[mt][1] - mnew);
      float e2 = __expf(scv[mt][2] - mnew);
      float e3 = __expf(scv[mt][3] - mnew);
      lsum += (e0 + e1) + (e2 + e3);
      union { bf16x4 v; uint2 u; } pu;
      pu.u.x = pack2(e0, e1); pu.u.y = pack2(e2, e3);
      pb[mt] = pu.v;
    }
    // V(t) ready: own parts via vmcnt, cross-wave via barrier
    if (t < 7) { WAITV4; } else { WAITV0; }
    BARW;
    // O^T += V^T @ P^T  (P^T straight from registers)
    PRIO1;
#pragma unroll
    for (int mt = 0; mt < 4; ++mt) {
      const int c2 = mt * 2 + (quad >> 1);
      const int sub = (quad & 1) * 4;
#pragma unroll
      for (int dt = 0; dt < 4; ++dt) {
        bf16x4 vf = *(const bf16x4*)&Vs[wv][(dt * 16 + l16) * 64 +
                                            ((c2 ^ (l16 & 7)) * 8) + sub];
        o4[dt] = mfma16_bf16(vf, pb[mt], o4[dt]);
      }
    }
    PRIO0;
    LGKM0;
    BARW;                 // all PV reads of Vs done -> safe to overwrite
    if (t < 7) ATT_STAGE_V(t + 1);
  }
  lsum += __shfl_xor(lsum, 16);
  lsum += __shfl_xor(lsum, 32);

  // merge the two KV halves via LDS (reuse Ks as fp32 scratch)
  float* MG = (float*)&Ks[0][0][0];
  const int mo = (wq * 64 + lane) * 18;
  if (wv == 1) {
    MG[mo] = mrun;
    MG[mo + 1] = lsum;
#pragma unroll
    for (int dt = 0; dt < 4; ++dt)
#pragma unroll
      for (int reg = 0; reg < 4; ++reg) MG[mo + 2 + dt * 4 + reg] = o4[dt][reg];
  }
  __syncthreads();
  if (wv == 0) {
    float m2 = MG[mo], l2 = MG[mo + 1];
    float mm = fmaxf(mrun, m2);
    float ca = __expf(mrun - mm), cb2 = __expf(m2 - mm);
    float inv = 1.f / (ca * lsum + cb2 * l2);
    short* op = &attnb[(size_t)(rowbase + qrow) * 256 + h * 64 + quad * 4];
#pragma unroll
    for (int dt = 0; dt < 4; ++dt) {
      float v0 = (ca * o4[dt][0] + cb2 * MG[mo + 2 + dt * 4 + 0]) * inv;
      float v1 = (ca * o4[dt][1] + cb2 * MG[mo + 2 + dt * 4 + 1]) * inv;
      float v2 = (ca * o4[dt][2] + cb2 * MG[mo + 2 + dt * 4 + 2]) * inv;
      float v3 = (ca * o4[dt][3] + cb2 * MG[mo + 2 + dt * 4 + 3]) * inv;
      uint2 uu;
      uu.x = pack2(v0, v1);
      uu.y = pack2(v2, v3);
      *(uint2*)&op[dt * 16] = uu;
    }
  }
#undef ATT_STAGE_K
#undef ATT_STAGE_V
}

// ---------- W1 GEMM (concat [x | attn]) + BN partial atomics.
// 1-D grid 512, XCD swizzle, cb-fast. Half-K resident, 80KB, 3 barriers.
__global__ __launch_bounds__(256, 2) void gemm_w1(
    const short* __restrict__ xb, const short* __restrict__ attnb,
    const short* __restrict__ w1t, const float* __restrict__ beff,
    float* __restrict__ hbuf, float* __restrict__ psumL, float* __restrict__ psqL) {
  __shared__ short SM[40960];     // 80KB exactly
  short* As = SM;                 // [4][2048]
  short* Bs = SM + 8192;          // [4][8192]
  const int bid = blockIdx.x;
  const int swz = (bid & 7) * 64 + (bid >> 3);   // 512/8 = 64
  const int rb = (swz >> 2) * 32, cb = (swz & 3) * 128;
  const int str = rb >> 11;      // stream for BN stats
  GEMM_IDS;
  floatx4 acc[4] = {z4, z4, z4, z4};

#pragma unroll
  for (int h = 0; h < 2; ++h) {
    if (h) BARW;                 // all reads of half-0 done before overwrite
    const short* Ap = (h == 0 ? xb : attnb) + (size_t)rb * 256;
#pragma unroll
    for (int st = 0; st < 4; ++st) {
      const int k0 = h * 256 + st * 64;
      gl2lds16(&Ap[(size_t)(w * 8 + lr) * 256 + st * 64 + lcs],
               &As[st * 2048 + (w * 8) * 64]);
#pragma unroll
      for (int i = 0; i < 4; ++i)
        gl2lds16(&w1t[(size_t)(cb + i * 32 + w * 8 + lr) * 512 + k0 + lcs],
                 &Bs[st * 8192 + (i * 32 + w * 8) * 64]);
    }
    WAITV0;
    BARW;
#pragma unroll
    for (int st = 0; st < 4; ++st)
      mfma_step_sw32(&As[st * 2048], &Bs[st * 8192], wy, wx, quad, l16, acc);
  }

  float colsum[4], colsq[4];
#pragma unroll
  for (int ni = 0; ni < 4; ++ni) { colsum[ni] = 0.f; colsq[ni] = 0.f; }
#pragma unroll
  for (int ni = 0; ni < 4; ++ni) {
    int col = wx * 64 + ni * 16 + l16;
    float bc = beff[cb + col];
#pragma unroll
    for (int reg = 0; reg < 4; ++reg) {
      int row = rb + wy * 16 + quad * 4 + reg;
      float val = acc[ni][reg] + bc;
      hbuf[(size_t)row * 512 + cb + col] = val;
      colsum[ni] += val; colsq[ni] += val * val;
    }
  }
#pragma unroll
  for (int ni = 0; ni < 4; ++ni)
#pragma unroll
    for (int d = 16; d < 64; d <<= 1) {
      colsum[ni] += __shfl_xor(colsum[ni], d);
      colsq[ni]  += __shfl_xor(colsq[ni], d);
    }
  __syncthreads();               // tile-buffer reads done; overlay Ps
  float (*Ps)[2][128] = (float(*)[2][128])SM;
  if (quad == 0) {
#pragma unroll
    for (int ni = 0; ni < 4; ++ni) {
      Ps[wy][0][wx * 64 + ni * 16 + l16] = colsum[ni];
      Ps[wy][1][wx * 64 + ni * 16 + l16] = colsq[ni];
    }
  }
  __syncthreads();
  if (tid < 128) {
    atomicAdd(&psumL[str * 512 + cb + tid], Ps[0][0][tid] + Ps[1][0][tid]);
    atomicAdd(&psqL [str * 512 + cb + tid], Ps[0][1][tid] + Ps[1][1][tid]);
  }
}

// ---------- W2: BN finalize + fused BN/ReLU A-staging + residual.
// 1-D grid 512, XCD swizzle, cb-fast. Half-K resident 52KB -> 3/CU, 3 barriers.
__global__ __launch_bounds__(256, 3) void gemm_w2(
    const float* __restrict__ hbuf, const short* __restrict__ w2t,
    const float* __restrict__ b2_, const float* __restrict__ psumL,
    const float* __restrict__ psqL, const float* __restrict__ g,
    const float* __restrict__ be, float* __restrict__ xd, short* __restrict__ xb,
    float* __restrict__ outp) {
  __shared__ short SM[24576];     // As [4][2048] | Bs [4][4096] = 48KB
  __shared__ float s_scale[512], s_shift[512];
  short* As = SM;
  short* Bs = SM + 8192;
  const int bid = blockIdx.x;
  const int swz = (bid & 7) * 64 + (bid >> 3);   // 512/8 = 64
  const int rb = (swz >> 2) * 32, cb = (swz & 3) * 64;
  const int str = rb >> 11;
  GEMM_IDS;
  floatx4 acc[2] = {z4, z4};
#pragma unroll
  for (int cc = 0; cc < 2; ++cc) {
    int c = tid + cc * 256;
    float sum = psumL[str * 512 + c];
    float sq  = psqL [str * 512 + c];
    float mean = sum * (1.f / 2048.f);
    float var = sq * (1.f / 2048.f) - mean * mean;
    float rstd = rsqrtf(var + 1e-5f);
    float gs = g[c] * rstd;
    s_scale[c] = gs;
    s_shift[c] = be[c] - mean * gs;
  }
  __syncthreads();

  const int p = tid & 7, ar = tid >> 3;   // ar 0..31

#pragma unroll
  for (int h = 0; h < 2; ++h) {
    if (h) BARW;
    // B first: 8 gl2lds16 in flight while A loads/transforms run
#pragma unroll
    for (int st = 0; st < 4; ++st) {
      const int k0 = h * 256 + st * 64;
#pragma unroll
      for (int i = 0; i < 2; ++i)
        gl2lds16(&w2t[(size_t)(cb + i * 32 + w * 8 + lr) * 512 + k0 + lcs],
                 &Bs[st * 4096 + (i * 32 + w * 8) * 64]);
    }
    // A: load hbuf, BN+ReLU, pack, LDS write
#pragma unroll
    for (int st = 0; st < 4; ++st) {
      const int cs = h * 256 + st * 64 + ((p ^ (ar & 7)) * 8);
      float4 h0 = *(const float4*)&hbuf[(size_t)(rb + ar) * 512 + cs];
      float4 h1 = *(const float4*)&hbuf[(size_t)(rb + ar) * 512 + cs + 4];
      float4 sc0 = *(const float4*)&s_scale[cs];
      float4 sc1 = *(const float4*)&s_scale[cs + 4];
      float4 sh0 = *(const float4*)&s_shift[cs];
      float4 sh1 = *(const float4*)&s_shift[cs + 4];
      uint4 pk;
      pk.x = pack2(fmaxf(h0.x * sc0.x + sh0.x, 0.f), fmaxf(h0.y * sc0.y + sh0.y, 0.f));
      pk.y = pack2(fmaxf(h0.z * sc0.z + sh0.z, 0.f), fmaxf(h0.w * sc0.w + sh0.w, 0.f));
      pk.z = pack2(fmaxf(h1.x * sc1.x + sh1.x, 0.f), fmaxf(h1.y * sc1.y + sh1.y, 0.f));
      pk.w = pack2(fmaxf(h1.z * sc1.z + sh1.z, 0.f), fmaxf(h1.w * sc1.w + sh1.w, 0.f));
      *(uint4*)&As[st * 2048 + ar * 64 + p * 8] = pk;
    }
    WAITV0;
    LGKM0;
    BARW;
#pragma unroll
    for (int st = 0; st < 4; ++st)
      mfma_step_sw32x64(&As[st * 2048], &Bs[st * 4096], wy, wx, quad, l16, acc);
  }

#pragma unroll
  for (int ni = 0; ni < 2; ++ni) {
    int col = cb + wx * 32 + ni * 16 + l16;
    float bc = b2_[col];
#pragma unroll
    for (int reg = 0; reg < 4; ++reg) {
      int row = rb + wy * 16 + quad * 4 + reg;
      float r = xd[(size_t)row * 256 + col] + acc[ni][reg] + bc;
      xd[(size_t)row * 256 + col] = r;
      xb[(size_t)row * 256 + col] = f2b(r);
      if (outp) {
        int ss = row >> 11, bb = (row >> 10) & 1, n = row & 1023;
        outp[(size_t)((bb * 2 + ss) * 1024 + n) * 256 + col] = r;
      }
    }
  }
}

extern "C" void kernel_launch(void* const* d_in, const int* in_sizes, int n_in,
                              void* d_out, int out_size, void* d_ws, size_t ws_size,
                              hipStream_t stream) {
  (void)in_sizes; (void)n_in; (void)out_size; (void)ws_size;
  const float* desc = (const float*)d_in[0];
  const int*   mask = (const int*)d_in[1];
  const float* qw = (const float*)d_in[2];
  const float* qb = (const float*)d_in[3];
  const float* kw = (const float*)d_in[4];
  const float* kb = (const float*)d_in[5];
  const float* vw = (const float*)d_in[6];
  const float* vb = (const float*)d_in[7];
  const float* ow = (const float*)d_in[8];
  const float* ob = (const float*)d_in[9];
  const float* w1 = (const float*)d_in[10];
  const float* b1 = (const float*)d_in[11];
  const float* bn_g = (const float*)d_in[12];
  const float* bn_b = (const float*)d_in[13];
  const float* w2 = (const float*)d_in[14];
  const float* b2 = (const float*)d_in[15];
  float* out = (float*)d_out;

  char* base = (char*)d_ws;
  float* xd    = (float*)(base);                  // [0,4) MB
  float* hbuf  = (float*)(base + (4u << 20));     // [4,12) MB
  short* xb    = (short*)(base + (12u << 20));
  short* qb16  = (short*)(base + (14u << 20));
  short* kb16  = (short*)(base + (16u << 20));
  short* vTb   = (short*)(base + (18u << 20));
  short* attnb = (short*)(base + (20u << 20));
  float* psum  = (float*)(base + (22u << 20));    // [18][2][512]
  float* psq   = psum + 18 * 1024;                // [18][2][512]
  float* beff  = psq + 18 * 1024;                 // 18*512 fp32
  short* wbuf  = (short*)(base + (24u << 20));    // 18*655360 shorts = 23.6 MB

  wprep<<<3508, 256, 0, stream>>>(qw, kw, vw, ow, w1, w2, ob, b1,
                                  wbuf, beff, desc, xd, xb, psum);

  for (int i = 0; i < 18; ++i) {
    int cross = i & 1;
    short* wb = wbuf + (size_t)i * 655360;

    gemm_qkv<<<768, 256, 0, stream>>>(
        xb, wb, qb + (size_t)i * 256, kb + (size_t)i * 256, vb + (size_t)i * 256,
        qb16, kb16, vTb, cross);
    attn_mfma<<<512, 256, 0, stream>>>(qb16, kb16, vTb, mask, attnb, cross);
    gemm_w1<<<512, 256, 0, stream>>>(xb, attnb, wb + 262144,
                                     beff + (size_t)i * 512,
                                     hbuf, psum + (size_t)i * 1024,
                                     psq + (size_t)i * 1024);
    gemm_w2<<<512, 256, 0, stream>>>(hbuf, wb + 524288,
                                     b2 + (size_t)i * 256,
                                     psum + (size_t)i * 1024,
                                     psq + (size_t)i * 1024,
                                     bn_g + (size_t)i * 512,
                                     bn_b + (size_t)i * 512, xd, xb,
                                     (i == 17) ? out : nullptr);
  }
}